// Round 1
// baseline (300.212 us; speedup 1.0000x reference)
//
#include <hip/hip_runtime.h>
#include <math.h>

// Problem constants (from reference setup): T=4, B=64, N=1024, P=63, D=128
#define T_STEPS 4
#define R_ROWS  65536              // B*N rows per timestep
#define M_ROWS  262144             // T*B*N total rows
#define P_DIM   63
#define D_DIM   128
#define PP      64                 // padded P (col 63 = virtual ones column in K1)

#define TILES_TOTAL (M_ROWS / 64)  // 4096 tiles of 64 rows
#define G_CHUNKS 8                 // reduce output copies consumed by stats

typedef float v4f __attribute__((ext_vector_type(4)));

// ---------------------------------------------------------------------------
// K1: per-block partial Gram  P_b = xa_b^T xa_b  (xa = x + ones column).
// r8 config restored (r9's single-wave 8x8 variant regressed: 128 fp64 VGPR
// accumulator -> ~1 wave/SIMD, latency exposed).  256 threads, 4x4 tiles,
// double-buffered LDS staging, fp64 per-block, plain coalesced stores.
// (unchanged in r11 — isolate the K3 change for clean attribution)
// ---------------------------------------------------------------------------
__global__ __launch_bounds__(256) void gram_kernel(const float* __restrict__ x,
                                                   double* __restrict__ partials,
                                                   int tiles_per_block) {
    __shared__ __align__(16) float xt[2][64 * PP];
    const int tid = threadIdx.x;
    const int tj = tid & 15;       // 16 col-tiles of 4
    const int ti = tid >> 4;       // 16 row-tiles of 4

    double dacc[4][4];
#pragma unroll
    for (int a = 0; a < 4; a++)
#pragma unroll
        for (int b = 0; b < 4; b++) dacc[a][b] = 0.0;

    if (tid < 64) {                // ones column in both buffers (never overwritten)
        xt[0][tid * PP + 63] = 1.0f;
        xt[1][tid * PP + 63] = 1.0f;
    }

    const int tile0 = blockIdx.x * tiles_per_block;
    float4 reg[4];

    {
        const float4* src = (const float4*)(x + (size_t)tile0 * (64 * 63));
#pragma unroll
        for (int it = 0; it < 4; it++) {
            int k = tid + it * 256;
            reg[it] = (k < 1008) ? src[k] : make_float4(0.f, 0.f, 0.f, 0.f);
        }
    }
#pragma unroll
    for (int it = 0; it < 4; it++) {
        int k = tid + it * 256;
        if (k < 1008) {
            const float* ve = (const float*)&reg[it];
            int flat = k * 4;
#pragma unroll
            for (int e = 0; e < 4; e++) {
                int f = flat + e;
                int r = f / 63;
                int c = f - r * 63;
                xt[0][r * PP + c] = ve[e];
            }
        }
    }
    __syncthreads();

    for (int t = 0; t < tiles_per_block; t++) {
        const int cur = t & 1;
        if (t + 1 < tiles_per_block) {
            const float4* src = (const float4*)(x + (size_t)(tile0 + t + 1) * (64 * 63));
#pragma unroll
            for (int it = 0; it < 4; it++) {
                int k = tid + it * 256;
                reg[it] = (k < 1008) ? src[k] : make_float4(0.f, 0.f, 0.f, 0.f);
            }
        }

        float facc[4][4];
#pragma unroll
        for (int a = 0; a < 4; a++)
#pragma unroll
            for (int b = 0; b < 4; b++) facc[a][b] = 0.0f;

        const float* buf = xt[cur];
        for (int r = 0; r < 64; r++) {
            float4 xi = *(const float4*)&buf[r * PP + ti * 4];
            float4 xj = *(const float4*)&buf[r * PP + tj * 4];
            const float* xia = (const float*)&xi;
            const float* xja = (const float*)&xj;
#pragma unroll
            for (int a = 0; a < 4; a++)
#pragma unroll
                for (int b = 0; b < 4; b++)
                    facc[a][b] = fmaf(xia[a], xja[b], facc[a][b]);
        }
#pragma unroll
        for (int a = 0; a < 4; a++)
#pragma unroll
            for (int b = 0; b < 4; b++) dacc[a][b] += (double)facc[a][b];

        __syncthreads();
        if (t + 1 < tiles_per_block) {
            float* nbuf = xt[1 - cur];
#pragma unroll
            for (int it = 0; it < 4; it++) {
                int k = tid + it * 256;
                if (k < 1008) {
                    const float* ve = (const float*)&reg[it];
                    int flat = k * 4;
#pragma unroll
                    for (int e = 0; e < 4; e++) {
                        int f = flat + e;
                        int r = f / 63;
                        int c = f - r * 63;
                        nbuf[r * PP + c] = ve[e];
                    }
                }
            }
            __syncthreads();
        }
    }

    double* Pb = partials + (size_t)blockIdx.x * 4096;
#pragma unroll
    for (int a = 0; a < 4; a++)
#pragma unroll
        for (int b = 0; b < 4; b++)
            Pb[(ti * 4 + a) * 64 + (tj * 4 + b)] = dacc[a][b];
}

// ---------------------------------------------------------------------------
// K1b: fold nparts partials into G_CHUNKS copies (deterministic fp64 sums).
// Blocks >= 128 instead build Wt[p*128+d] = W[d*63+p] (needed by lif; folded
// here to avoid an extra launch — runs in dispatch-parallel with the folds).
// ---------------------------------------------------------------------------
__global__ __launch_bounds__(256) void reduce_kernel(const double* __restrict__ partials,
                                                     double* __restrict__ G8,
                                                     const float* __restrict__ W,
                                                     float* __restrict__ Wt,
                                                     int copies_per_chunk) {
    if (blockIdx.x >= G_CHUNKS * 16) {
        int widx = (blockIdx.x - G_CHUNKS * 16) * 256 + threadIdx.x;
        for (int j = widx; j < P_DIM * D_DIM; j += 8 * 256) {
            int p = j >> 7;
            int d = j & 127;
            Wt[j] = W[d * P_DIM + p];
        }
        return;
    }
    const int chunk = blockIdx.x >> 4;             // 0..7
    const int idx   = (blockIdx.x & 15) * 256 + threadIdx.x;  // 0..4095
    const double* src = partials + (size_t)chunk * copies_per_chunk * 4096;
    double s = 0.0;
    for (int c = 0; c < copies_per_chunk; c++)
        s += src[(size_t)c * 4096 + idx];
    G8[(size_t)chunk * 4096 + idx] = s;
}

// ---------------------------------------------------------------------------
// K2: per-channel stats.  mean_d = (colsum . W_d)/M ; E[h^2]_d = W_d G W_d^T / M
// var = E[h^2] - mean^2 (fp64).  stats[d] = {mean, invstd, gamma, beta}.
// ---------------------------------------------------------------------------
__global__ __launch_bounds__(64) void stats_kernel(const double* __restrict__ G,
                                                   const float* __restrict__ W,
                                                   const float* __restrict__ gamma,
                                                   const float* __restrict__ beta,
                                                   float* __restrict__ stats) {
    const int d = blockIdx.x;    // 0..127
    const int p = threadIdx.x;   // 0..63
    __shared__ float sW[64];
    sW[p] = (p < P_DIM) ? W[d * P_DIM + p] : 0.0f;
    __syncthreads();

    double inner = 0.0;
#pragma unroll
    for (int c = 0; c < G_CHUNKS; c++) {
        const double* Gr = G + (size_t)c * (64 * 64) + p * 64;
        for (int q = 0; q < 64; q++) inner += Gr[q] * (double)sW[q];
    }

    double contrib = (double)sW[p] * inner;   // row 63 has w=0 -> no effect
    double ex2M = contrib;
#pragma unroll
    for (int off = 32; off > 0; off >>= 1) ex2M += __shfl_down(ex2M, off, 64);
    double meanM = __shfl(inner, 63, 64);     // ones-row dot W_d = colsum . W_d

    if (p == 0) {
        double mean = meanM / (double)M_ROWS;
        double ex2  = ex2M  / (double)M_ROWS;
        double var  = ex2 - mean * mean;
        float varf  = (float)var;
        float vpe   = varf + 1e-5f;                 // ref: fp32 var + fp32 eps
        float invstd = (float)(1.0 / sqrt((double)vpe));
        stats[d * 4 + 0] = (float)mean;
        stats[d * 4 + 1] = invstd;
        stats[d * 4 + 2] = gamma[d];
        stats[d * 4 + 3] = beta[d];
    }
}

// ---------------------------------------------------------------------------
// K3: on-the-fly GEMM + BN affine (ref op order) + 4-step LIF in registers.
// Round-11: r10's VALU trim bought only ~3us of the ~30us of targeted VALU
// => K3 is NOT VALU-bound.  The per-CU-shared LDS read pipe is the limiter:
// r10 issued 12 ds_read_b128 per 128 FMAs (~55us of CU LDS-pipe time vs 27us
// of FMA).  Fix: 8ch x 8row-instance register tile (acc[8][8], 256 FMA per
// 16 LDS reads, -33% LDS instr/FMA), 32 rows/block (2048 blocks -> staging/
// barrier/epilogue overhead per row halves).  LDS 65KB -> 2 blocks/CU,
// __launch_bounds__(256,2) frees VGPRs to 256.  fmaf chains per accumulator
// remain ascending-p identical -> bitwise-identical h.
// ---------------------------------------------------------------------------
#define LIF_ROWS 32
#define SX_STRIDE 64
__global__ __launch_bounds__(256, 2) void lif_kernel(const float* __restrict__ x,
                                                     const float* __restrict__ Wt,
                                                     const float* __restrict__ stats,
                                                     float* __restrict__ out) {
    __shared__ __align__(16) float sw[P_DIM * D_DIM];                   // 32256 B
    __shared__ __align__(16) float sx[T_STEPS * LIF_ROWS * SX_STRIDE];  // 32768 B
    const int tid = threadIdx.x;

    // stage Wt: flat float4 copy (2016 float4), conflict-free, no div
    {
        const float4* wt4 = (const float4*)Wt;
        float4* sw4 = (float4*)sw;
#pragma unroll
        for (int i = 0; i < 8; i++) {
            int k = tid + i * 256;
            if (k < 2016) sw4[k] = wt4[k];
        }
    }

    // stage x: flat coalesced nontemporal float4 loads, scatter into stride-64
    // 32 rows x 63 = 2016 floats = 504 float4 per timestep-segment
    const int r0 = blockIdx.x * LIF_ROWS;
    const int seg = tid >> 6;      // timestep
    const int lane = tid & 63;
    const v4f* src = (const v4f*)(x + ((size_t)seg * R_ROWS + r0) * P_DIM);
#pragma unroll
    for (int kk = 0; kk < 8; kk++) {
        int k = lane + kk * 64;    // < 512; 504 valid
        v4f v;
        if (k < 504) v = __builtin_nontemporal_load(&src[k]);
        if (k < 504) {
            int flat = k * 4;
#pragma unroll
            for (int e = 0; e < 4; e++) {
                int f = flat + e;
                int r = f / 63;
                int c = f - r * 63;
                sx[(seg * LIF_ROWS + r) * SX_STRIDE + c] = v[e];
            }
        }
    }
    __syncthreads();

    const int td = tid & 15;      // 16 channel-tiles of 8
    const int tr = tid >> 4;      // 16 row-pairs
    const int d0 = td * 8;
    const int rowa = tr * 2;

    float acc[8][8];              // [t*2+i][j]  j = channel d0+j
#pragma unroll
    for (int u = 0; u < 8; u++)
#pragma unroll
        for (int j = 0; j < 8; j++) acc[u][j] = 0.0f;

    // main loop: 15 p-quads, FULLY UNROLLED (imm ds offsets)
    // per pq: 8 w-reads + 8 x-reads (b128) feed 256 FMAs
#pragma unroll
    for (int pq = 0; pq < 15; pq++) {
        const int p = pq * 4;
        float4 wa[4], wb[4];
#pragma unroll
        for (int pp = 0; pp < 4; pp++) {
            wa[pp] = *(const float4*)&sw[(p + pp) * D_DIM + d0];
            wb[pp] = *(const float4*)&sw[(p + pp) * D_DIM + d0 + 4];
        }
#pragma unroll
        for (int t = 0; t < T_STEPS; t++)
#pragma unroll
            for (int i = 0; i < 2; i++) {
                float4 xv = *(const float4*)&sx[(t * LIF_ROWS + rowa + i) * SX_STRIDE + p];
                const float xs[4] = {xv.x, xv.y, xv.z, xv.w};
                float* a = acc[t * 2 + i];
#pragma unroll
                for (int pp = 0; pp < 4; pp++) {   // ascending p within quad
                    a[0] = fmaf(xs[pp], wa[pp].x, a[0]);
                    a[1] = fmaf(xs[pp], wa[pp].y, a[1]);
                    a[2] = fmaf(xs[pp], wa[pp].z, a[2]);
                    a[3] = fmaf(xs[pp], wa[pp].w, a[3]);
                    a[4] = fmaf(xs[pp], wb[pp].x, a[4]);
                    a[5] = fmaf(xs[pp], wb[pp].y, a[5]);
                    a[6] = fmaf(xs[pp], wb[pp].z, a[6]);
                    a[7] = fmaf(xs[pp], wb[pp].w, a[7]);
                }
            }
    }
    // tail: p = 60, 61, 62 (same ascending order)
#pragma unroll
    for (int p = 60; p < 63; p++) {
        float4 wa = *(const float4*)&sw[p * D_DIM + d0];
        float4 wb = *(const float4*)&sw[p * D_DIM + d0 + 4];
#pragma unroll
        for (int t = 0; t < T_STEPS; t++)
#pragma unroll
            for (int i = 0; i < 2; i++) {
                float xv = sx[(t * LIF_ROWS + rowa + i) * SX_STRIDE + p];
                float* a = acc[t * 2 + i];
                a[0] = fmaf(xv, wa.x, a[0]);
                a[1] = fmaf(xv, wa.y, a[1]);
                a[2] = fmaf(xv, wa.z, a[2]);
                a[3] = fmaf(xv, wa.w, a[3]);
                a[4] = fmaf(xv, wb.x, a[4]);
                a[5] = fmaf(xv, wb.y, a[5]);
                a[6] = fmaf(xv, wb.z, a[6]);
                a[7] = fmaf(xv, wb.w, a[7]);
            }
    }

    // epilogue: BN affine (ref op order) + LIF scan; nontemporal b128 stores
#pragma unroll
    for (int i = 0; i < 2; i++) {
        const int row = r0 + rowa + i;
        float sval[T_STEPS][8];
#pragma unroll
        for (int j = 0; j < 8; j++) {
            float4 st = ((const float4*)stats)[d0 + j];  // mean, invstd, gamma, beta
            float v = 0.0f;
#pragma unroll
            for (int t = 0; t < T_STEPS; t++) {
                float hn = (acc[t * 2 + i][j] - st.x) * st.y;
                hn = hn * st.z;
                hn = hn + st.w;
                v = v + (hn - v) * 0.5f;       // == v + (x-v)/2, exact
                float s = (v >= 1.0f) ? 1.0f : 0.0f;  // (v-1>=0) sign-exact
                sval[t][j] = s;
                if (s != 0.0f) v = 0.0f;       // hard reset
            }
        }
#pragma unroll
        for (int t = 0; t < T_STEPS; t++) {
            v4f o0 = {sval[t][0], sval[t][1], sval[t][2], sval[t][3]};
            v4f o1 = {sval[t][4], sval[t][5], sval[t][6], sval[t][7]};
            __builtin_nontemporal_store(
                o0, (v4f*)&out[((size_t)t * R_ROWS + row) * D_DIM + d0]);
            __builtin_nontemporal_store(
                o1, (v4f*)&out[((size_t)t * R_ROWS + row) * D_DIM + d0 + 4]);
        }
    }
}

// ---------------------------------------------------------------------------
extern "C" void kernel_launch(void* const* d_in, const int* in_sizes, int n_in,
                              void* d_out, int out_size, void* d_ws, size_t ws_size,
                              hipStream_t stream) {
    const float* x     = (const float*)d_in[0];
    const float* W     = (const float*)d_in[1];
    const float* gamma = (const float*)d_in[2];
    const float* beta  = (const float*)d_in[3];
    float* out = (float*)d_out;

    // pick partial count by available workspace (power of 2, 64..512)
    const size_t fixed = (size_t)G_CHUNKS * 4096 * 8 + 2048 + 32768 + 4096;
    int nparts = 512;
    while (nparts > 64 && (size_t)nparts * 4096 * 8 + fixed > ws_size) nparts >>= 1;
    const int tiles_per_block = TILES_TOTAL / nparts;

    double* partials = (double*)d_ws;
    double* G8       = (double*)((char*)d_ws + (size_t)nparts * 4096 * 8);
    float*  stats    = (float*)((char*)G8 + (size_t)G_CHUNKS * 4096 * 8);
    float*  Wt       = (float*)((char*)stats + 2048);

    gram_kernel<<<nparts, 256, 0, stream>>>(x, partials, tiles_per_block);
    reduce_kernel<<<G_CHUNKS * 16 + 8, 256, 0, stream>>>(partials, G8, W, Wt,
                                                         nparts / G_CHUNKS);
    stats_kernel<<<D_DIM, 64, 0, stream>>>(G8, W, gamma, beta, stats);
    lif_kernel<<<R_ROWS / LIF_ROWS, 256, 0, stream>>>(x, Wt, stats, out);
}